// Round 4
// baseline (847.609 us; speedup 1.0000x reference)
//
#include <hip/hip_runtime.h>
#include <stdint.h>

// MHA fused: B=16384, T=32, C=128, H=4, HD=32, fp32 in/out.
// One wave per batch element. bf16 MFMA with hi/lo split on the Q/K path.
// R4: LDS eliminated entirely. All fragment re-layouts (q/k/att/v/O) are done
// in-register: bf16 pack + v_permlane32_swap (2 swaps per fragment). The
// permlane r[0]/r[1] orientation ambiguity cancels because both operands of
// every permlane-fed MFMA (QK^T, PV) are built identically (k-permutation
// invariance); the proj 'of' fragment (mixed with plain weight frags) uses
// known-semantics __shfl_xor instead. exp computed once. 3-chain Q proj ILP.
// R6: fix compile error — plswap outputs via local scalars (vector elements
// cannot bind to non-const references).
// R7: identical resubmit (R6 bench was lost to GPUAcquisitionTimeout).

typedef __bf16   bf16x8 __attribute__((ext_vector_type(8)));
typedef uint16_t u16x8  __attribute__((ext_vector_type(8)));
typedef uint32_t u32x4  __attribute__((ext_vector_type(4)));
typedef float    f32x16 __attribute__((ext_vector_type(16)));

#define T_  32
#define C_  128
#define NH_ 4

// ws element offsets (bf16 units). Fragment arrays [grp][kk][lane][8]:
// value = W[row=lane&31][col = kk*16 + (lane>>5)*8 + j] of a 32x128 slice.
#define OQHI 0
#define OQLO 16384
#define OKHI 32768
#define OKLO 49152
#define OVHI 65536
#define OWP  81920

__device__ __forceinline__ uint32_t bfbits(float f) {
  // round-to-nearest-even bf16, returned as fp32 bit pattern (low 16 zero)
  uint32_t u = __float_as_uint(f);
  return (u + 0x7FFFu + ((u >> 16) & 1u)) & 0xFFFF0000u;
}

__global__ void prep_weights(const float* __restrict__ Wq, const float* __restrict__ Wk,
                             const float* __restrict__ Wv, const float* __restrict__ Wp,
                             uint16_t* __restrict__ ws) {
  int tid = blockIdx.x * 256 + threadIdx.x;      // 8192 threads
  int sec = tid >> 11;                           // 0=Q 1=K 2=V 3=Wp
  int g   = tid & 2047;
  int l   = g & 63;
  int kk  = (g >> 6) & 7;
  int hh  = g >> 9;
  int row  = l & 31;
  int col0 = kk * 16 + (l >> 5) * 8;
  const float* srcs[4] = {Wq, Wk, Wv, Wp};
  const float* p = srcs[sec] + (hh * 32 + row) * 128 + col0;
  u16x8 hi, lo;
#pragma unroll
  for (int j = 0; j < 8; j++) {
    float f = p[j];
    uint32_t hb = bfbits(f);
    float lf = f - __uint_as_float(hb);
    hi[j] = (uint16_t)(hb >> 16);
    lo[j] = (uint16_t)(bfbits(lf) >> 16);
  }
  u16x8* w8 = (u16x8*)ws;
  if      (sec == 0) { w8[OQHI / 8 + g] = hi; w8[OQLO / 8 + g] = lo; }
  else if (sec == 1) { w8[OKHI / 8 + g] = hi; w8[OKLO / 8 + g] = lo; }
  else if (sec == 2) { w8[OVHI / 8 + g] = hi; }
  else               { w8[OWP  / 8 + g] = hi; }
}

__device__ __forceinline__ f32x16 mfma_bf16(u16x8 a, u16x8 b, f32x16 c) {
  return __builtin_amdgcn_mfma_f32_32x32x16_bf16(
      __builtin_bit_cast(bf16x8, a), __builtin_bit_cast(bf16x8, b), c, 0, 0, 0);
}

__device__ __forceinline__ float trunch(float f) {
  return __uint_as_float(__float_as_uint(f) & 0xFFFF0000u);
}
__device__ __forceinline__ uint32_t pack_hi2(float f0, float f1) {
  return (__float_as_uint(f1) & 0xFFFF0000u) | (__float_as_uint(f0) >> 16);
}
// RNE bf16 pair pack (compiler emits v_cvt_pk_bf16_f32 or equivalent)
__device__ __forceinline__ uint32_t pack_rne2(float f0, float f1) {
  __bf16 b0 = (__bf16)f0, b1 = (__bf16)f1;
  return (uint32_t)__builtin_bit_cast(uint16_t, b0) |
         ((uint32_t)__builtin_bit_cast(uint16_t, b1) << 16);
}

// Build an 8-element bf16 fragment (lane holds elements k = 8*half + j,
// j=0..7 of the 16-wide k-slice) from 4 packed dwords:
// pa0=pack(v0,v1), pa1=pack(v2,v3), pb0=pack(v4,v5), pb1=pack(v6,v7)
// where v0..v7 are the lane's D-layout regs [8*ks .. 8*ks+8).
// One permlane32_swap yields both fragment words ({a.lo,b.lo},{a.hi,b.hi});
// the r[0]/r[1] orientation ambiguity flips frag words w<->w^2 (k-index
// j->j^4), which cancels when both MFMA operands use this builder.
__device__ __forceinline__ u16x8 frag4(uint32_t pa0, uint32_t pa1,
                                       uint32_t pb0, uint32_t pb1) {
  auto r0 = __builtin_amdgcn_permlane32_swap(pa0, pb0, false, false);
  auto r1 = __builtin_amdgcn_permlane32_swap(pa1, pb1, false, false);
  u32x4 d;
  d[0] = (uint32_t)r0[0];
  d[1] = (uint32_t)r1[0];
  d[2] = (uint32_t)r0[1];
  d[3] = (uint32_t)r1[1];
  return __builtin_bit_cast(u16x8, d);
}

// hi/lo split packs for one 8-float group: ph/pl[0..3] = {PA0,PA1,PB0,PB1}
__device__ __forceinline__ void packs_hilo(const float* f, uint32_t* ph, uint32_t* pl) {
#pragma unroll
  for (int p = 0; p < 4; p++) {
    float f0 = f[2 * p], f1 = f[2 * p + 1];
    ph[p] = pack_hi2(f0, f1);
    pl[p] = pack_rne2(f0 - trunch(f0), f1 - trunch(f1));
  }
}

#define SCALE 11.313708498984760390f

__global__ __launch_bounds__(256, 3)
void mha_main(const float* __restrict__ x, const uint16_t* __restrict__ ws,
              const float* __restrict__ bp, float* __restrict__ out) {
  const int lane = threadIdx.x & 63;
  const int wid  = threadIdx.x >> 6;
  const int half = lane >> 5;
  const int rc   = lane & 31;
  const int b    = blockIdx.x * 4 + wid;

  const u16x8* w8  = (const u16x8*)ws;
  const u16x8* WQH = w8 + OQHI / 8;
  const u16x8* WQL = w8 + OQLO / 8;
  const u16x8* WKH = w8 + OKHI / 8;
  const u16x8* WKL = w8 + OKLO / 8;
  const u16x8* WVH = w8 + OVHI / 8;
  const u16x8* WPH = w8 + OWP  / 8;

  // x as B-fragments [t=lane&31][c], trunc-hi + exact-lo split, in regs.
  u16x8 xhi[8], xlo[8];
  const float* xb = x + (size_t)b * (T_ * C_) + rc * C_ + half * 8;
#pragma unroll
  for (int kk = 0; kk < 8; kk++) {
    float4 f0 = *(const float4*)(xb + kk * 16);
    float4 f1 = *(const float4*)(xb + kk * 16 + 4);
    float vv[8] = {f0.x, f0.y, f0.z, f0.w, f1.x, f1.y, f1.z, f1.w};
    u32x4 hw, lw;
#pragma unroll
    for (int p = 0; p < 4; p++) {
      float a = vv[2 * p], c = vv[2 * p + 1];
      hw[p] = pack_hi2(a, c);
      lw[p] = pack_rne2(a - trunch(a), c - trunch(c));
    }
    xhi[kk] = __builtin_bit_cast(u16x8, hw);
    xlo[kk] = __builtin_bit_cast(u16x8, lw);
  }

  f32x16 facc[4] = {};

#pragma unroll 1
  for (int h = 0; h < NH_; h++) {
    // ---- Q = x@Wq^T (swapped): D lane = t, reg = d. 3 independent chains.
    uint32_t qph[8], qpl[8];
    {
      f32x16 a0 = {}, a1 = {}, a2 = {};
#pragma unroll
      for (int kk = 0; kk < 8; kk++) {
        u16x8 wh = WQH[(h * 8 + kk) * 64 + lane];
        u16x8 wl = WQL[(h * 8 + kk) * 64 + lane];
        a0 = mfma_bf16(wh, xhi[kk], a0);
        a1 = mfma_bf16(wl, xhi[kk], a1);
        a2 = mfma_bf16(wh, xlo[kk], a2);
      }
#pragma unroll
      for (int ks = 0; ks < 2; ks++) {
        float f[8];
#pragma unroll
        for (int i = 0; i < 8; i++)
          f[i] = a0[8 * ks + i] + a1[8 * ks + i] + a2[8 * ks + i];
        packs_hilo(f, &qph[4 * ks], &qpl[4 * ks]);
      }
    }
    // ---- K, then S^T = K @ Q^T fused per ks (keeps c-pressure short-lived).
    f32x16 s0 = {}, s1 = {};
    {
      f32x16 c0 = {}, c1 = {};
#pragma unroll
      for (int kk = 0; kk < 8; kk++) {
        u16x8 wh = WKH[(h * 8 + kk) * 64 + lane];
        u16x8 wl = WKL[(h * 8 + kk) * 64 + lane];
        c0 = mfma_bf16(wh, xhi[kk], c0);
        c1 = mfma_bf16(wl, xhi[kk], c1);
        c1 = mfma_bf16(wh, xlo[kk], c1);
      }
#pragma unroll
      for (int ks = 0; ks < 2; ks++) {
        float f[8];
#pragma unroll
        for (int i = 0; i < 8; i++)
          f[i] = c0[8 * ks + i] + c1[8 * ks + i];
        uint32_t kh[4], kl[4];
        packs_hilo(f, kh, kl);
        u16x8 khf = frag4(kh[0], kh[1], kh[2], kh[3]);
        u16x8 klf = frag4(kl[0], kl[1], kl[2], kl[3]);
        u16x8 qhf = frag4(qph[4 * ks + 0], qph[4 * ks + 1], qph[4 * ks + 2], qph[4 * ks + 3]);
        u16x8 qlf = frag4(qpl[4 * ks + 0], qpl[4 * ks + 1], qpl[4 * ks + 2], qpl[4 * ks + 3]);
        s0 = mfma_bf16(khf, qhf, s0);
        s1 = mfma_bf16(klf, qhf, s1);
        s1 = mfma_bf16(khf, qlf, s1);
      }
    }
    // ---- V = x@Wv^T (unswapped): D lane = d, reg = s. Independent of S;
    // issued here to fill the S-mfma latency shadow.
    f32x16 v0 = {};
#pragma unroll
    for (int kk = 0; kk < 8; kk++)
      v0 = mfma_bf16(xhi[kk], WVH[(h * 8 + kk) * 64 + lane], v0);
    // ---- softmax over s (reg dim); t = rc. exp computed ONCE into s0.
#pragma unroll
    for (int r = 0; r < 16; r++) s0[r] += s1[r];
    float mx = -3.0e38f;
#pragma unroll
    for (int r = 0; r < 16; r++) {
      int s = (r & 3) + 8 * (r >> 2) + 4 * half;
      if (s <= rc) mx = fmaxf(mx, s0[r]);
    }
    mx = fmaxf(mx, __shfl_xor(mx, 32, 64));
    float sum = 0.0f;
#pragma unroll
    for (int r = 0; r < 16; r++) {
      int s = (r & 3) + 8 * (r >> 2) + 4 * half;
      float e = (s <= rc) ? __expf((s0[r] - mx) * SCALE) : 0.0f;
      s0[r] = e;
      sum += e;
    }
    sum += __shfl_xor(sum, 32, 64);
    float rs = __builtin_amdgcn_rcpf(sum);
    // ---- O = mfma(A=v-frag, B=att-frag): D lane = t, reg = d.
    f32x16 o = {};
#pragma unroll
    for (int ks = 0; ks < 2; ks++) {
      uint32_t ap[4], vp[4];
#pragma unroll
      for (int p = 0; p < 4; p++) {
        ap[p] = pack_rne2(s0[8 * ks + 2 * p] * rs, s0[8 * ks + 2 * p + 1] * rs);
        vp[p] = pack_rne2(v0[8 * ks + 2 * p], v0[8 * ks + 2 * p + 1]);
      }
      u16x8 af = frag4(ap[0], ap[1], ap[2], ap[3]);
      u16x8 vf = frag4(vp[0], vp[1], vp[2], vp[3]);
      o = mfma_bf16(vf, af, o);
    }
    // ---- out-projection. 'of' frag via __shfl_xor (exact semantics; this
    // MFMA mixes a permlane-free weight operand so invariance doesn't apply).
#pragma unroll
    for (int kp = 0; kp < 2; kp++) {
      uint32_t pa0 = pack_rne2(o[8 * kp + 0], o[8 * kp + 1]);
      uint32_t pa1 = pack_rne2(o[8 * kp + 2], o[8 * kp + 3]);
      uint32_t pb0 = pack_rne2(o[8 * kp + 4], o[8 * kp + 5]);
      uint32_t pb1 = pack_rne2(o[8 * kp + 6], o[8 * kp + 7]);
      uint32_t sa0 = (uint32_t)__shfl_xor((int)pa0, 32, 64);
      uint32_t sa1 = (uint32_t)__shfl_xor((int)pa1, 32, 64);
      uint32_t sb0 = (uint32_t)__shfl_xor((int)pb0, 32, 64);
      uint32_t sb1 = (uint32_t)__shfl_xor((int)pb1, 32, 64);
      u32x4 d;
      d[0] = half ? sb0 : pa0;
      d[1] = half ? sb1 : pa1;
      d[2] = half ? pb0 : sa0;
      d[3] = half ? pb1 : sa1;
      u16x8 of = __builtin_bit_cast(u16x8, d);
#pragma unroll
      for (int nt = 0; nt < 4; nt++)
        facc[nt] = mfma_bf16(of, WPH[(nt * 8 + h * 2 + kp) * 64 + lane], facc[nt]);
    }
  }

  // ---- store with bias; lanes 0..31 cover 128B contiguous per (nt, r).
  float* ob = out + (size_t)b * (T_ * C_);
  float bpv[4];
#pragma unroll
  for (int nt = 0; nt < 4; nt++) bpv[nt] = bp[nt * 32 + rc];
#pragma unroll
  for (int nt = 0; nt < 4; nt++) {
#pragma unroll
    for (int r = 0; r < 16; r++) {
      int t = (r & 3) + 8 * (r >> 2) + 4 * half;
      ob[t * 128 + nt * 32 + rc] = facc[nt][r] + bpv[nt];
    }
  }
}

extern "C" void kernel_launch(void* const* d_in, const int* in_sizes, int n_in,
                              void* d_out, int out_size, void* d_ws, size_t ws_size,
                              hipStream_t stream) {
  const float* x  = (const float*)d_in[0];
  const float* Wq = (const float*)d_in[1];
  const float* Wk = (const float*)d_in[2];
  const float* Wv = (const float*)d_in[3];
  const float* Wp = (const float*)d_in[4];
  const float* bp = (const float*)d_in[5];
  uint16_t* wf = (uint16_t*)d_ws;
  prep_weights<<<32, 256, 0, stream>>>(Wq, Wk, Wv, Wp, wf);
  mha_main<<<4096, 256, 0, stream>>>(x, wf, bp, (float*)d_out);
}

// Round 5
// 557.523 us; speedup vs baseline: 1.5203x; 1.5203x over previous
//
#include <hip/hip_runtime.h>
#include <stdint.h>

// MHA fused: B=16384, T=32, C=128, H=4, HD=32, fp32 in/out.
// One wave per batch element. bf16 MFMA with hi/lo split on the Q/K path.
// R4/R6: LDS eliminated; fragment re-layouts via bf16 pack + permlane32_swap
// (orientation ambiguity cancels: both operands of QK^T / PV built identically;
// proj 'of' frag uses exact __shfl_xor). Verified on HW: bank conflicts = 0,
// absmax unchanged. But R6 SPILLED (~1 GB scratch writes): in-loop live set
// ~200 VGPR > 170 cap from launch_bounds(256,3).
// R8: kill the spill. (a) out-projection DEFERRED to epilogue — per-head
// packed 'of' frags stashed (8 dw/head, scalar-uniform select, static idx),
// freeing facc(64) from the loop; identical accumulation order => bit-equal.
// (b) Q proj 2 chains, S^T single chain. In-loop peak ~148 regs < 170.

typedef __bf16   bf16x8 __attribute__((ext_vector_type(8)));
typedef uint16_t u16x8  __attribute__((ext_vector_type(8)));
typedef uint32_t u32x4  __attribute__((ext_vector_type(4)));
typedef float    f32x16 __attribute__((ext_vector_type(16)));

#define T_  32
#define C_  128
#define NH_ 4

// ws element offsets (bf16 units). Fragment arrays [grp][kk][lane][8]:
// value = W[row=lane&31][col = kk*16 + (lane>>5)*8 + j] of a 32x128 slice.
#define OQHI 0
#define OQLO 16384
#define OKHI 32768
#define OKLO 49152
#define OVHI 65536
#define OWP  81920

__device__ __forceinline__ uint32_t bfbits(float f) {
  // round-to-nearest-even bf16, returned as fp32 bit pattern (low 16 zero)
  uint32_t u = __float_as_uint(f);
  return (u + 0x7FFFu + ((u >> 16) & 1u)) & 0xFFFF0000u;
}

__global__ void prep_weights(const float* __restrict__ Wq, const float* __restrict__ Wk,
                             const float* __restrict__ Wv, const float* __restrict__ Wp,
                             uint16_t* __restrict__ ws) {
  int tid = blockIdx.x * 256 + threadIdx.x;      // 8192 threads
  int sec = tid >> 11;                           // 0=Q 1=K 2=V 3=Wp
  int g   = tid & 2047;
  int l   = g & 63;
  int kk  = (g >> 6) & 7;
  int hh  = g >> 9;
  int row  = l & 31;
  int col0 = kk * 16 + (l >> 5) * 8;
  const float* srcs[4] = {Wq, Wk, Wv, Wp};
  const float* p = srcs[sec] + (hh * 32 + row) * 128 + col0;
  u16x8 hi, lo;
#pragma unroll
  for (int j = 0; j < 8; j++) {
    float f = p[j];
    uint32_t hb = bfbits(f);
    float lf = f - __uint_as_float(hb);
    hi[j] = (uint16_t)(hb >> 16);
    lo[j] = (uint16_t)(bfbits(lf) >> 16);
  }
  u16x8* w8 = (u16x8*)ws;
  if      (sec == 0) { w8[OQHI / 8 + g] = hi; w8[OQLO / 8 + g] = lo; }
  else if (sec == 1) { w8[OKHI / 8 + g] = hi; w8[OKLO / 8 + g] = lo; }
  else if (sec == 2) { w8[OVHI / 8 + g] = hi; }
  else               { w8[OWP  / 8 + g] = hi; }
}

__device__ __forceinline__ f32x16 mfma_bf16(u16x8 a, u16x8 b, f32x16 c) {
  return __builtin_amdgcn_mfma_f32_32x32x16_bf16(
      __builtin_bit_cast(bf16x8, a), __builtin_bit_cast(bf16x8, b), c, 0, 0, 0);
}

__device__ __forceinline__ float trunch(float f) {
  return __uint_as_float(__float_as_uint(f) & 0xFFFF0000u);
}
__device__ __forceinline__ uint32_t pack_hi2(float f0, float f1) {
  return (__float_as_uint(f1) & 0xFFFF0000u) | (__float_as_uint(f0) >> 16);
}
// RNE bf16 pair pack (compiler emits v_cvt_pk_bf16_f32 or equivalent)
__device__ __forceinline__ uint32_t pack_rne2(float f0, float f1) {
  __bf16 b0 = (__bf16)f0, b1 = (__bf16)f1;
  return (uint32_t)__builtin_bit_cast(uint16_t, b0) |
         ((uint32_t)__builtin_bit_cast(uint16_t, b1) << 16);
}

// Build an 8-element bf16 fragment (lane holds elements k = 8*half + j,
// j=0..7 of the 16-wide k-slice) from 4 packed dwords:
// pa0=pack(v0,v1), pa1=pack(v2,v3), pb0=pack(v4,v5), pb1=pack(v6,v7)
// where v0..v7 are the lane's D-layout regs [8*ks .. 8*ks+8).
// One permlane32_swap yields both fragment words ({a.lo,b.lo},{a.hi,b.hi});
// the r[0]/r[1] orientation ambiguity flips frag words w<->w^2 (k-index
// j->j^4), which cancels when both MFMA operands use this builder.
__device__ __forceinline__ u16x8 frag4(uint32_t pa0, uint32_t pa1,
                                       uint32_t pb0, uint32_t pb1) {
  auto r0 = __builtin_amdgcn_permlane32_swap(pa0, pb0, false, false);
  auto r1 = __builtin_amdgcn_permlane32_swap(pa1, pb1, false, false);
  u32x4 d;
  d[0] = (uint32_t)r0[0];
  d[1] = (uint32_t)r1[0];
  d[2] = (uint32_t)r0[1];
  d[3] = (uint32_t)r1[1];
  return __builtin_bit_cast(u16x8, d);
}

// hi/lo split packs for one 8-float group: ph/pl[0..3] = {PA0,PA1,PB0,PB1}
__device__ __forceinline__ void packs_hilo(const float* f, uint32_t* ph, uint32_t* pl) {
#pragma unroll
  for (int p = 0; p < 4; p++) {
    float f0 = f[2 * p], f1 = f[2 * p + 1];
    ph[p] = pack_hi2(f0, f1);
    pl[p] = pack_rne2(f0 - trunch(f0), f1 - trunch(f1));
  }
}

#define SCALE 11.313708498984760390f

__global__ __launch_bounds__(256, 3)
void mha_main(const float* __restrict__ x, const uint16_t* __restrict__ ws,
              const float* __restrict__ bp, float* __restrict__ out) {
  const int lane = threadIdx.x & 63;
  const int wid  = threadIdx.x >> 6;
  const int half = lane >> 5;
  const int rc   = lane & 31;
  const int b    = blockIdx.x * 4 + wid;

  const u16x8* w8  = (const u16x8*)ws;
  const u16x8* WQH = w8 + OQHI / 8;
  const u16x8* WQL = w8 + OQLO / 8;
  const u16x8* WKH = w8 + OKHI / 8;
  const u16x8* WKL = w8 + OKLO / 8;
  const u16x8* WVH = w8 + OVHI / 8;
  const u16x8* WPH = w8 + OWP  / 8;

  // x as B-fragments [t=lane&31][c], trunc-hi + exact-lo split, in regs.
  u16x8 xhi[8], xlo[8];
  const float* xb = x + (size_t)b * (T_ * C_) + rc * C_ + half * 8;
#pragma unroll
  for (int kk = 0; kk < 8; kk++) {
    float4 f0 = *(const float4*)(xb + kk * 16);
    float4 f1 = *(const float4*)(xb + kk * 16 + 4);
    float vv[8] = {f0.x, f0.y, f0.z, f0.w, f1.x, f1.y, f1.z, f1.w};
    u32x4 hw, lw;
#pragma unroll
    for (int p = 0; p < 4; p++) {
      float a = vv[2 * p], c = vv[2 * p + 1];
      hw[p] = pack_hi2(a, c);
      lw[p] = pack_rne2(a - trunch(a), c - trunch(c));
    }
    xhi[kk] = __builtin_bit_cast(u16x8, hw);
    xlo[kk] = __builtin_bit_cast(u16x8, lw);
  }

  // Per-head packed proj-input fragments, stashed for the epilogue.
  // Scalar-uniform select on h keeps all indexing static (no scratch).
  u32x4 ofs0[2] = {}, ofs1[2] = {}, ofs2[2] = {}, ofs3[2] = {};

#pragma unroll 1
  for (int h = 0; h < NH_; h++) {
    // ---- Q = x@Wq^T (swapped): D lane = t, reg = d. 2 chains.
    uint32_t qph[8], qpl[8];
    {
      f32x16 a0 = {}, a1 = {};
#pragma unroll
      for (int kk = 0; kk < 8; kk++) {
        u16x8 wh = WQH[(h * 8 + kk) * 64 + lane];
        u16x8 wl = WQL[(h * 8 + kk) * 64 + lane];
        a0 = mfma_bf16(wh, xhi[kk], a0);
        a1 = mfma_bf16(wl, xhi[kk], a1);
        a1 = mfma_bf16(wh, xlo[kk], a1);
      }
#pragma unroll
      for (int ks = 0; ks < 2; ks++) {
        float f[8];
#pragma unroll
        for (int i = 0; i < 8; i++)
          f[i] = a0[8 * ks + i] + a1[8 * ks + i];
        packs_hilo(f, &qph[4 * ks], &qpl[4 * ks]);
      }
    }
    // ---- K, then S^T = K @ Q^T fused per ks. Single S chain (reg relief).
    f32x16 s0 = {};
    {
      f32x16 c0 = {}, c1 = {};
#pragma unroll
      for (int kk = 0; kk < 8; kk++) {
        u16x8 wh = WKH[(h * 8 + kk) * 64 + lane];
        u16x8 wl = WKL[(h * 8 + kk) * 64 + lane];
        c0 = mfma_bf16(wh, xhi[kk], c0);
        c1 = mfma_bf16(wl, xhi[kk], c1);
        c1 = mfma_bf16(wh, xlo[kk], c1);
      }
#pragma unroll
      for (int ks = 0; ks < 2; ks++) {
        float f[8];
#pragma unroll
        for (int i = 0; i < 8; i++)
          f[i] = c0[8 * ks + i] + c1[8 * ks + i];
        uint32_t kh[4], kl[4];
        packs_hilo(f, kh, kl);
        u16x8 khf = frag4(kh[0], kh[1], kh[2], kh[3]);
        u16x8 klf = frag4(kl[0], kl[1], kl[2], kl[3]);
        u16x8 qhf = frag4(qph[4 * ks + 0], qph[4 * ks + 1], qph[4 * ks + 2], qph[4 * ks + 3]);
        u16x8 qlf = frag4(qpl[4 * ks + 0], qpl[4 * ks + 1], qpl[4 * ks + 2], qpl[4 * ks + 3]);
        s0 = mfma_bf16(khf, qhf, s0);
        s0 = mfma_bf16(klf, qhf, s0);
        s0 = mfma_bf16(khf, qlf, s0);
      }
    }
    // ---- V = x@Wv^T (unswapped): D lane = d, reg = s. Independent of S;
    // issued here to fill the S-mfma latency shadow.
    f32x16 v0 = {};
#pragma unroll
    for (int kk = 0; kk < 8; kk++)
      v0 = mfma_bf16(xhi[kk], WVH[(h * 8 + kk) * 64 + lane], v0);
    // ---- softmax over s (reg dim); t = rc. exp computed ONCE into s0.
    float mx = -3.0e38f;
#pragma unroll
    for (int r = 0; r < 16; r++) {
      int s = (r & 3) + 8 * (r >> 2) + 4 * half;
      if (s <= rc) mx = fmaxf(mx, s0[r]);
    }
    mx = fmaxf(mx, __shfl_xor(mx, 32, 64));
    float sum = 0.0f;
#pragma unroll
    for (int r = 0; r < 16; r++) {
      int s = (r & 3) + 8 * (r >> 2) + 4 * half;
      float e = (s <= rc) ? __expf((s0[r] - mx) * SCALE) : 0.0f;
      s0[r] = e;
      sum += e;
    }
    sum += __shfl_xor(sum, 32, 64);
    float rs = __builtin_amdgcn_rcpf(sum);
    // ---- O = mfma(A=v-frag, B=att-frag): D lane = t, reg = d.
    f32x16 o = {};
#pragma unroll
    for (int ks = 0; ks < 2; ks++) {
      uint32_t ap[4], vp[4];
#pragma unroll
      for (int p = 0; p < 4; p++) {
        ap[p] = pack_rne2(s0[8 * ks + 2 * p] * rs, s0[8 * ks + 2 * p + 1] * rs);
        vp[p] = pack_rne2(v0[8 * ks + 2 * p], v0[8 * ks + 2 * p + 1]);
      }
      u16x8 af = frag4(ap[0], ap[1], ap[2], ap[3]);
      u16x8 vf = frag4(vp[0], vp[1], vp[2], vp[3]);
      o = mfma_bf16(vf, af, o);
    }
    // ---- build proj 'of' frags via __shfl_xor (exact semantics) and stash.
#pragma unroll
    for (int kp = 0; kp < 2; kp++) {
      uint32_t pa0 = pack_rne2(o[8 * kp + 0], o[8 * kp + 1]);
      uint32_t pa1 = pack_rne2(o[8 * kp + 2], o[8 * kp + 3]);
      uint32_t pb0 = pack_rne2(o[8 * kp + 4], o[8 * kp + 5]);
      uint32_t pb1 = pack_rne2(o[8 * kp + 6], o[8 * kp + 7]);
      uint32_t sa0 = (uint32_t)__shfl_xor((int)pa0, 32, 64);
      uint32_t sa1 = (uint32_t)__shfl_xor((int)pa1, 32, 64);
      uint32_t sb0 = (uint32_t)__shfl_xor((int)pb0, 32, 64);
      uint32_t sb1 = (uint32_t)__shfl_xor((int)pb1, 32, 64);
      u32x4 d;
      d[0] = half ? sb0 : pa0;
      d[1] = half ? sb1 : pa1;
      d[2] = half ? pb0 : sa0;
      d[3] = half ? pb1 : sa1;
      if      (h == 0) ofs0[kp] = d;
      else if (h == 1) ofs1[kp] = d;
      else if (h == 2) ofs2[kp] = d;
      else             ofs3[kp] = d;
    }
  }

  // ---- epilogue: out-projection over all stashed head fragments.
  // Same h-major, kp-minor accumulation order as before => bit-identical.
  f32x16 facc[4] = {};
#pragma unroll
  for (int h2 = 0; h2 < NH_; h2++) {
#pragma unroll
    for (int kp = 0; kp < 2; kp++) {
      u32x4 dv = (h2 == 0) ? ofs0[kp] : (h2 == 1) ? ofs1[kp]
               : (h2 == 2) ? ofs2[kp] : ofs3[kp];
      u16x8 of = __builtin_bit_cast(u16x8, dv);
#pragma unroll
      for (int nt = 0; nt < 4; nt++)
        facc[nt] = mfma_bf16(of, WPH[(nt * 8 + h2 * 2 + kp) * 64 + lane], facc[nt]);
    }
  }

  // ---- store with bias; lanes 0..31 cover 128B contiguous per (nt, r).
  float* ob = out + (size_t)b * (T_ * C_);
  float bpv[4];
#pragma unroll
  for (int nt = 0; nt < 4; nt++) bpv[nt] = bp[nt * 32 + rc];
#pragma unroll
  for (int nt = 0; nt < 4; nt++) {
#pragma unroll
    for (int r = 0; r < 16; r++) {
      int t = (r & 3) + 8 * (r >> 2) + 4 * half;
      ob[t * 128 + nt * 32 + rc] = facc[nt][r] + bpv[nt];
    }
  }
}

extern "C" void kernel_launch(void* const* d_in, const int* in_sizes, int n_in,
                              void* d_out, int out_size, void* d_ws, size_t ws_size,
                              hipStream_t stream) {
  const float* x  = (const float*)d_in[0];
  const float* Wq = (const float*)d_in[1];
  const float* Wk = (const float*)d_in[2];
  const float* Wv = (const float*)d_in[3];
  const float* Wp = (const float*)d_in[4];
  const float* bp = (const float*)d_in[5];
  uint16_t* wf = (uint16_t*)d_ws;
  prep_weights<<<32, 256, 0, stream>>>(Wq, Wk, Wv, Wp, wf);
  mha_main<<<4096, 256, 0, stream>>>(x, wf, bp, (float*)d_out);
}